// Round 1
// baseline (886.581 us; speedup 1.0000x reference)
//
#include <hip/hip_runtime.h>
#include <hip/hip_bf16.h>
#include <math.h>

#define B 2
#define S 2048
#define D 1024
#define H 16
#define HD 64
#define SCALE 0.125f

#define BM 128
#define BN 128
#define BK 16
#define LDT (BM + 4)  // 132, keeps float4 LDS reads aligned, conflicts <=2-way (free)

// ---------------- document span bounds (ids are sorted) ----------------
__global__ void docbounds_k(const int* __restrict__ doc, int* __restrict__ dstart,
                            int* __restrict__ dend) {
    int i = blockIdx.x * blockDim.x + threadIdx.x;
    if (i >= S) return;
    int v = doc[i];
    int lo = 0, hi = S;
    while (lo < hi) { int mid = (lo + hi) >> 1; if (doc[mid] < v) lo = mid + 1; else hi = mid; }
    dstart[i] = lo;
    lo = 0; hi = S;
    while (lo < hi) { int mid = (lo + hi) >> 1; if (doc[mid] <= v) lo = mid + 1; else hi = mid; }
    dend[i] = lo;
}

// ---------------- fused QKV projection: Y = X @ W^T + b, fp32 ----------------
// X: (B*S, D) row-major; W: (D, D) row-major (rows = output features).
// Output written in (B, H, S, HD) layout.
__global__ __launch_bounds__(256) void qkv_gemm_k(
    const float* __restrict__ X,
    const float* __restrict__ wq, const float* __restrict__ bq,
    const float* __restrict__ wk, const float* __restrict__ bk,
    const float* __restrict__ wv, const float* __restrict__ bv,
    float* __restrict__ Qo, float* __restrict__ Ko, float* __restrict__ Vo)
{
    const int which = blockIdx.z;
    const float* Wm   = (which == 0) ? wq : (which == 1) ? wk : wv;
    const float* bias = (which == 0) ? bq : (which == 1) ? bk : bv;
    float* Y          = (which == 0) ? Qo : (which == 1) ? Ko : Vo;

    __shared__ float As[BK][LDT];
    __shared__ float Bs[BK][LDT];

    const int tid = threadIdx.x;
    const int tx = tid & 15, ty = tid >> 4;
    const int m0 = blockIdx.y * BM, n0 = blockIdx.x * BN;

    float acc[8][8];
    #pragma unroll
    for (int i = 0; i < 8; i++)
        #pragma unroll
        for (int j = 0; j < 8; j++) acc[i][j] = 0.f;

    for (int k0 = 0; k0 < D; k0 += BK) {
        #pragma unroll
        for (int p = 0; p < 2; p++) {
            int e = tid + p * 256;
            int row = e >> 2;
            int kc = (e & 3) << 2;
            const float4 a4 = *(const float4*)(X + (size_t)(m0 + row) * D + k0 + kc);
            As[kc + 0][row] = a4.x; As[kc + 1][row] = a4.y;
            As[kc + 2][row] = a4.z; As[kc + 3][row] = a4.w;
            const float4 b4 = *(const float4*)(Wm + (size_t)(n0 + row) * D + k0 + kc);
            Bs[kc + 0][row] = b4.x; Bs[kc + 1][row] = b4.y;
            Bs[kc + 2][row] = b4.z; Bs[kc + 3][row] = b4.w;
        }
        __syncthreads();
        #pragma unroll
        for (int kk = 0; kk < BK; kk++) {
            float4 a0 = *(const float4*)&As[kk][ty * 8];
            float4 a1 = *(const float4*)&As[kk][ty * 8 + 4];
            float4 b0 = *(const float4*)&Bs[kk][tx * 8];
            float4 b1 = *(const float4*)&Bs[kk][tx * 8 + 4];
            float a[8] = {a0.x, a0.y, a0.z, a0.w, a1.x, a1.y, a1.z, a1.w};
            float b[8] = {b0.x, b0.y, b0.z, b0.w, b1.x, b1.y, b1.z, b1.w};
            #pragma unroll
            for (int i = 0; i < 8; i++)
                #pragma unroll
                for (int j = 0; j < 8; j++) acc[i][j] += a[i] * b[j];
        }
        __syncthreads();
    }

    // epilogue: remap (m, n) -> (b, h, s, hd)
    #pragma unroll
    for (int i = 0; i < 8; i++) {
        int m = m0 + ty * 8 + i;
        int bb = m >> 11;       // m / S
        int s  = m & (S - 1);
        #pragma unroll
        for (int j = 0; j < 8; j++) {
            int n = n0 + tx * 8 + j;
            int h = n >> 6, hd = n & 63;
            Y[((size_t)((bb * H + h) * S) + s) * HD + hd] = acc[i][j] + bias[n];
        }
    }
}

// ---------------- output projection: out = O @ Wo^T + bo ----------------
__global__ __launch_bounds__(256) void out_gemm_k(
    const float* __restrict__ X, const float* __restrict__ Wm,
    const float* __restrict__ bias, float* __restrict__ Y)
{
    __shared__ float As[BK][LDT];
    __shared__ float Bs[BK][LDT];

    const int tid = threadIdx.x;
    const int tx = tid & 15, ty = tid >> 4;
    const int m0 = blockIdx.y * BM, n0 = blockIdx.x * BN;

    float acc[8][8];
    #pragma unroll
    for (int i = 0; i < 8; i++)
        #pragma unroll
        for (int j = 0; j < 8; j++) acc[i][j] = 0.f;

    for (int k0 = 0; k0 < D; k0 += BK) {
        #pragma unroll
        for (int p = 0; p < 2; p++) {
            int e = tid + p * 256;
            int row = e >> 2;
            int kc = (e & 3) << 2;
            const float4 a4 = *(const float4*)(X + (size_t)(m0 + row) * D + k0 + kc);
            As[kc + 0][row] = a4.x; As[kc + 1][row] = a4.y;
            As[kc + 2][row] = a4.z; As[kc + 3][row] = a4.w;
            const float4 b4 = *(const float4*)(Wm + (size_t)(n0 + row) * D + k0 + kc);
            Bs[kc + 0][row] = b4.x; Bs[kc + 1][row] = b4.y;
            Bs[kc + 2][row] = b4.z; Bs[kc + 3][row] = b4.w;
        }
        __syncthreads();
        #pragma unroll
        for (int kk = 0; kk < BK; kk++) {
            float4 a0 = *(const float4*)&As[kk][ty * 8];
            float4 a1 = *(const float4*)&As[kk][ty * 8 + 4];
            float4 b0 = *(const float4*)&Bs[kk][tx * 8];
            float4 b1 = *(const float4*)&Bs[kk][tx * 8 + 4];
            float a[8] = {a0.x, a0.y, a0.z, a0.w, a1.x, a1.y, a1.z, a1.w};
            float b[8] = {b0.x, b0.y, b0.z, b0.w, b1.x, b1.y, b1.z, b1.w};
            #pragma unroll
            for (int i = 0; i < 8; i++)
                #pragma unroll
                for (int j = 0; j < 8; j++) acc[i][j] += a[i] * b[j];
        }
        __syncthreads();
    }

    #pragma unroll
    for (int i = 0; i < 8; i++) {
        int m = m0 + ty * 8 + i;
        #pragma unroll
        for (int j = 0; j < 8; j++) {
            int n = n0 + tx * 8 + j;
            Y[(size_t)m * D + n] = acc[i][j] + bias[n];
        }
    }
}

// ---------------- block-diagonal flash attention ----------------
// One wave (64 lanes) per (b, h, query row). Q/K/V in (B,H,S,HD) layout.
// Output O in (B, S, H*HD) = (B,S,D) layout for the final GEMM.
__global__ __launch_bounds__(64) void attn_k(
    const float* __restrict__ Q, const float* __restrict__ K,
    const float* __restrict__ V, const int* __restrict__ dstart,
    const int* __restrict__ dend, float* __restrict__ O)
{
    const int i = blockIdx.x, h = blockIdx.y, b = blockIdx.z;
    const int d = threadIdx.x;
    const size_t bh = ((size_t)b * H + h) * S;

    __shared__ float qs[HD];
    __shared__ float ps[64];

    qs[d] = Q[(bh + i) * HD + d] * SCALE;
    __syncthreads();

    const int start = dstart[i], end = dend[i];
    float m = -INFINITY, l = 0.f, o = 0.f;

    for (int j0 = start; j0 < end; j0 += 64) {
        int j = j0 + d;
        int jr = (j < end) ? j : (end - 1);
        const float* krow = K + (bh + jr) * HD;
        float s = 0.f;
        #pragma unroll
        for (int c = 0; c < HD / 4; c++) {
            float4 k4 = *(const float4*)(krow + c * 4);
            s += qs[c * 4 + 0] * k4.x + qs[c * 4 + 1] * k4.y +
                 qs[c * 4 + 2] * k4.z + qs[c * 4 + 3] * k4.w;
        }
        if (j >= end) s = -INFINITY;

        float wm = s;
        #pragma unroll
        for (int off = 32; off >= 1; off >>= 1) wm = fmaxf(wm, __shfl_xor(wm, off, 64));
        float m_new = fmaxf(m, wm);
        float alpha = __expf(m - m_new);
        float p = (j < end) ? __expf(s - m_new) : 0.f;
        float psum = p;
        #pragma unroll
        for (int off = 32; off >= 1; off >>= 1) psum += __shfl_xor(psum, off, 64);
        l = l * alpha + psum;

        ps[d] = p;
        __syncthreads();

        o *= alpha;
        int lim = end - j0; if (lim > 64) lim = 64;
        const float* vbase = V + (bh + j0) * HD + d;
        for (int jj = 0; jj < lim; jj++) {
            o += ps[jj] * vbase[(size_t)jj * HD];
        }
        m = m_new;
        __syncthreads();
    }

    // O layout: (B, S, H, HD) flat = (B, S, D)
    O[((size_t)(b * S + i) * H + h) * HD + d] = o / l;
}

extern "C" void kernel_launch(void* const* d_in, const int* in_sizes, int n_in,
                              void* d_out, int out_size, void* d_ws, size_t ws_size,
                              hipStream_t stream) {
    const float* hs = (const float*)d_in[0];
    const float* wq = (const float*)d_in[1];
    const float* bq = (const float*)d_in[2];
    const float* wk = (const float*)d_in[3];
    const float* bk = (const float*)d_in[4];
    const float* wv = (const float*)d_in[5];
    const float* bv = (const float*)d_in[6];
    const float* wo = (const float*)d_in[7];
    const float* bo = (const float*)d_in[8];
    const int*  doc = (const int*)d_in[9];
    float* out = (float*)d_out;

    const size_t NE = (size_t)B * S * D;  // 4,194,304
    float* Qb = (float*)d_ws;
    float* Kb = Qb + NE;
    float* Vb = Kb + NE;
    float* Ob = Vb + NE;
    int* dstart = (int*)(Ob + NE);
    int* dend = dstart + S;

    docbounds_k<<<(S + 255) / 256, 256, 0, stream>>>(doc, dstart, dend);
    qkv_gemm_k<<<dim3(D / BN, (B * S) / BM, 3), 256, 0, stream>>>(
        hs, wq, bq, wk, bk, wv, bv, Qb, Kb, Vb);
    attn_k<<<dim3(S, H, B), 64, 0, stream>>>(Qb, Kb, Vb, dstart, dend, Ob);
    out_gemm_k<<<dim3(D / BN, (B * S) / BM), 256, 0, stream>>>(Ob, wo, bo, out);
}

// Round 2
// 743.758 us; speedup vs baseline: 1.1920x; 1.1920x over previous
//
#include <hip/hip_runtime.h>
#include <hip/hip_bf16.h>
#include <math.h>

#define B 2
#define S 2048
#define D 1024
#define H 16
#define HD 64
#define SCALE 0.125f
#define NEGBIG -1e30f

#define BM 128
#define BN 128
#define BK 16
#define LDT (BM + 4)

#define TQ 64   // queries per attention block
#define TK 64   // keys per chunk

// ---------------- document span bounds (ids are sorted) ----------------
__global__ void docbounds_k(const int* __restrict__ doc, int* __restrict__ dstart,
                            int* __restrict__ dend) {
    int i = blockIdx.x * blockDim.x + threadIdx.x;
    if (i >= S) return;
    int v = doc[i];
    int lo = 0, hi = S;
    while (lo < hi) { int mid = (lo + hi) >> 1; if (doc[mid] < v) lo = mid + 1; else hi = mid; }
    dstart[i] = lo;
    lo = 0; hi = S;
    while (lo < hi) { int mid = (lo + hi) >> 1; if (doc[mid] <= v) lo = mid + 1; else hi = mid; }
    dend[i] = lo;
}

// ---------------- fused QKV projection: Y = X @ W^T + b, fp32 ----------------
__global__ __launch_bounds__(256) void qkv_gemm_k(
    const float* __restrict__ X,
    const float* __restrict__ wq, const float* __restrict__ bq,
    const float* __restrict__ wk, const float* __restrict__ bk,
    const float* __restrict__ wv, const float* __restrict__ bv,
    float* __restrict__ Qo, float* __restrict__ Ko, float* __restrict__ Vo)
{
    const int which = blockIdx.z;
    const float* Wm   = (which == 0) ? wq : (which == 1) ? wk : wv;
    const float* bias = (which == 0) ? bq : (which == 1) ? bk : bv;
    float* Y          = (which == 0) ? Qo : (which == 1) ? Ko : Vo;

    __shared__ float As[BK][LDT];
    __shared__ float Bs[BK][LDT];

    const int tid = threadIdx.x;
    const int tx = tid & 15, ty = tid >> 4;
    const int m0 = blockIdx.y * BM, n0 = blockIdx.x * BN;

    float acc[8][8];
    #pragma unroll
    for (int i = 0; i < 8; i++)
        #pragma unroll
        for (int j = 0; j < 8; j++) acc[i][j] = 0.f;

    for (int k0 = 0; k0 < D; k0 += BK) {
        #pragma unroll
        for (int p = 0; p < 2; p++) {
            int e = tid + p * 256;
            int row = e >> 2;
            int kc = (e & 3) << 2;
            const float4 a4 = *(const float4*)(X + (size_t)(m0 + row) * D + k0 + kc);
            As[kc + 0][row] = a4.x; As[kc + 1][row] = a4.y;
            As[kc + 2][row] = a4.z; As[kc + 3][row] = a4.w;
            const float4 b4 = *(const float4*)(Wm + (size_t)(n0 + row) * D + k0 + kc);
            Bs[kc + 0][row] = b4.x; Bs[kc + 1][row] = b4.y;
            Bs[kc + 2][row] = b4.z; Bs[kc + 3][row] = b4.w;
        }
        __syncthreads();
        #pragma unroll
        for (int kk = 0; kk < BK; kk++) {
            float4 a0 = *(const float4*)&As[kk][ty * 8];
            float4 a1 = *(const float4*)&As[kk][ty * 8 + 4];
            float4 b0 = *(const float4*)&Bs[kk][tx * 8];
            float4 b1 = *(const float4*)&Bs[kk][tx * 8 + 4];
            float a[8] = {a0.x, a0.y, a0.z, a0.w, a1.x, a1.y, a1.z, a1.w};
            float b[8] = {b0.x, b0.y, b0.z, b0.w, b1.x, b1.y, b1.z, b1.w};
            #pragma unroll
            for (int i = 0; i < 8; i++)
                #pragma unroll
                for (int j = 0; j < 8; j++) acc[i][j] += a[i] * b[j];
        }
        __syncthreads();
    }

    #pragma unroll
    for (int i = 0; i < 8; i++) {
        int m = m0 + ty * 8 + i;
        int bb = m >> 11;
        int s  = m & (S - 1);
        #pragma unroll
        for (int j = 0; j < 8; j++) {
            int n = n0 + tx * 8 + j;
            int h = n >> 6, hd = n & 63;
            Y[((size_t)((bb * H + h) * S) + s) * HD + hd] = acc[i][j] + bias[n];
        }
    }
}

// ---------------- output projection: out = O @ Wo^T + bo ----------------
__global__ __launch_bounds__(256) void out_gemm_k(
    const float* __restrict__ X, const float* __restrict__ Wm,
    const float* __restrict__ bias, float* __restrict__ Y)
{
    __shared__ float As[BK][LDT];
    __shared__ float Bs[BK][LDT];

    const int tid = threadIdx.x;
    const int tx = tid & 15, ty = tid >> 4;
    const int m0 = blockIdx.y * BM, n0 = blockIdx.x * BN;

    float acc[8][8];
    #pragma unroll
    for (int i = 0; i < 8; i++)
        #pragma unroll
        for (int j = 0; j < 8; j++) acc[i][j] = 0.f;

    for (int k0 = 0; k0 < D; k0 += BK) {
        #pragma unroll
        for (int p = 0; p < 2; p++) {
            int e = tid + p * 256;
            int row = e >> 2;
            int kc = (e & 3) << 2;
            const float4 a4 = *(const float4*)(X + (size_t)(m0 + row) * D + k0 + kc);
            As[kc + 0][row] = a4.x; As[kc + 1][row] = a4.y;
            As[kc + 2][row] = a4.z; As[kc + 3][row] = a4.w;
            const float4 b4 = *(const float4*)(Wm + (size_t)(n0 + row) * D + k0 + kc);
            Bs[kc + 0][row] = b4.x; Bs[kc + 1][row] = b4.y;
            Bs[kc + 2][row] = b4.z; Bs[kc + 3][row] = b4.w;
        }
        __syncthreads();
        #pragma unroll
        for (int kk = 0; kk < BK; kk++) {
            float4 a0 = *(const float4*)&As[kk][ty * 8];
            float4 a1 = *(const float4*)&As[kk][ty * 8 + 4];
            float4 b0 = *(const float4*)&Bs[kk][tx * 8];
            float4 b1 = *(const float4*)&Bs[kk][tx * 8 + 4];
            float a[8] = {a0.x, a0.y, a0.z, a0.w, a1.x, a1.y, a1.z, a1.w};
            float b[8] = {b0.x, b0.y, b0.z, b0.w, b1.x, b1.y, b1.z, b1.w};
            #pragma unroll
            for (int i = 0; i < 8; i++)
                #pragma unroll
                for (int j = 0; j < 8; j++) acc[i][j] += a[i] * b[j];
        }
        __syncthreads();
    }

    #pragma unroll
    for (int i = 0; i < 8; i++) {
        int m = m0 + ty * 8 + i;
        #pragma unroll
        for (int j = 0; j < 8; j++) {
            int n = n0 + tx * 8 + j;
            Y[(size_t)m * D + n] = acc[i][j] + bias[n];
        }
    }
}

// ---------------- block-diagonal flash attention, query-tiled ----------------
// 256 threads / block; block handles TQ=64 queries for one (b,h).
// Wave w owns queries w*16 .. w*16+15.
// Score phase: lane = key (K row in registers, Q broadcast from LDS).
// V phase: lane = dim (V chunk in LDS, P via per-wave LDS slab).
__global__ __launch_bounds__(256) void attn2_k(
    const float* __restrict__ Q, const float* __restrict__ K,
    const float* __restrict__ V, const int* __restrict__ dstart,
    const int* __restrict__ dend, float* __restrict__ O)
{
    const int qt = blockIdx.x, h = blockIdx.y, b = blockIdx.z;
    const int q0 = qt * TQ;
    const size_t bh = ((size_t)b * H + h) * S;

    const int tid = threadIdx.x;
    const int lane = tid & 63;
    const int w = tid >> 6;

    __shared__ float qs[TQ][HD];        // scaled Q tile
    __shared__ float Vs[TK][HD];        // V chunk
    __shared__ float Ps[4][16][TK];     // per-wave P slab
    __shared__ int sstart[TQ], send[TQ];

    // stage scaled Q (1024 float4s, 4 per thread)
    #pragma unroll
    for (int p = 0; p < 4; p++) {
        int e = tid + p * 256;
        int i = e >> 4, c = e & 15;
        float4 q4 = *(const float4*)(Q + (bh + q0 + i) * HD + c * 4);
        float4* dst = (float4*)&qs[i][c * 4];
        *dst = make_float4(q4.x * SCALE, q4.y * SCALE, q4.z * SCALE, q4.w * SCALE);
    }
    if (tid < TQ) {
        sstart[tid] = dstart[q0 + tid];
        send[tid]   = dend[q0 + tid];
    }
    __syncthreads();

    const int kstart = sstart[0];
    const int kend   = send[TQ - 1];

    float m_i[16], l_i[16], o_i[16], alpha[16];
    #pragma unroll
    for (int i = 0; i < 16; i++) { m_i[i] = NEGBIG; l_i[i] = 0.f; o_i[i] = 0.f; }

    for (int j0 = kstart; j0 < kend; j0 += TK) {
        // ---- stage V chunk ----
        #pragma unroll
        for (int p = 0; p < 4; p++) {
            int e = tid + p * 256;
            int j = e >> 4, c = e & 15;
            int jr = j0 + j; if (jr > S - 1) jr = S - 1;
            *(float4*)&Vs[j][c * 4] = *(const float4*)(V + (bh + jr) * HD + c * 4);
        }
        __syncthreads();

        // ---- score phase: lane = key ----
        int jme = j0 + lane;
        int jclamp = (jme > S - 1) ? (S - 1) : jme;
        float4 kreg[16];
        const float4* kp = (const float4*)(K + (bh + jclamp) * HD);
        #pragma unroll
        for (int c = 0; c < 16; c++) kreg[c] = kp[c];

        #pragma unroll
        for (int i = 0; i < 16; i++) {
            const int il = w * 16 + i;
            const float4* q4p = (const float4*)&qs[il][0];
            float s = 0.f;
            #pragma unroll
            for (int c = 0; c < 16; c++) {
                float4 q4 = q4p[c];
                s += q4.x * kreg[c].x + q4.y * kreg[c].y +
                     q4.z * kreg[c].z + q4.w * kreg[c].w;
            }
            const int st = sstart[il], en = send[il];
            const bool valid = (jme >= st) && (jme < en);
            float sv = valid ? s : NEGBIG;

            float wm = sv;
            #pragma unroll
            for (int off = 32; off >= 1; off >>= 1) wm = fmaxf(wm, __shfl_xor(wm, off, 64));
            float m_new = fmaxf(m_i[i], wm);
            alpha[i] = __expf(m_i[i] - m_new);
            float p = valid ? __expf(sv - m_new) : 0.f;
            float psum = p;
            #pragma unroll
            for (int off = 32; off >= 1; off >>= 1) psum += __shfl_xor(psum, off, 64);
            l_i[i] = l_i[i] * alpha[i] + psum;
            m_i[i] = m_new;
            o_i[i] *= alpha[i];         // alpha is lane-uniform; o_i semantic is lane=dim
            Ps[w][i][lane] = p;
        }

        // ---- V phase: lane = dim ----
        #pragma unroll 4
        for (int jj = 0; jj < TK; jj += 4) {
            float v0 = Vs[jj + 0][lane];
            float v1 = Vs[jj + 1][lane];
            float v2 = Vs[jj + 2][lane];
            float v3 = Vs[jj + 3][lane];
            #pragma unroll
            for (int i = 0; i < 16; i++) {
                float4 p4 = *(const float4*)&Ps[w][i][jj];
                o_i[i] = fmaf(p4.x, v0, fmaf(p4.y, v1, fmaf(p4.z, v2, fmaf(p4.w, v3, o_i[i]))));
            }
        }
        __syncthreads();   // protect Vs against next-iteration overwrite
    }

    // epilogue: O layout (B, S, H, HD) flat = (B, S, D); lane = dim
    #pragma unroll
    for (int i = 0; i < 16; i++) {
        const int il = w * 16 + i;
        const int iq = q0 + il;
        float inv = 1.f / l_i[i];
        O[((size_t)(b * S + iq) * H + h) * HD + lane] = o_i[i] * inv;
    }
}

extern "C" void kernel_launch(void* const* d_in, const int* in_sizes, int n_in,
                              void* d_out, int out_size, void* d_ws, size_t ws_size,
                              hipStream_t stream) {
    const float* hs = (const float*)d_in[0];
    const float* wq = (const float*)d_in[1];
    const float* bq = (const float*)d_in[2];
    const float* wk = (const float*)d_in[3];
    const float* bk = (const float*)d_in[4];
    const float* wv = (const float*)d_in[5];
    const float* bv = (const float*)d_in[6];
    const float* wo = (const float*)d_in[7];
    const float* bo = (const float*)d_in[8];
    const int*  doc = (const int*)d_in[9];
    float* out = (float*)d_out;

    const size_t NE = (size_t)B * S * D;
    float* Qb = (float*)d_ws;
    float* Kb = Qb + NE;
    float* Vb = Kb + NE;
    float* Ob = Vb + NE;
    int* dstart = (int*)(Ob + NE);
    int* dend = dstart + S;

    docbounds_k<<<(S + 255) / 256, 256, 0, stream>>>(doc, dstart, dend);
    qkv_gemm_k<<<dim3(D / BN, (B * S) / BM, 3), 256, 0, stream>>>(
        hs, wq, bq, wk, bk, wv, bv, Qb, Kb, Vb);
    attn2_k<<<dim3(S / TQ, H, B), 256, 0, stream>>>(Qb, Kb, Vb, dstart, dend, Ob);
    out_gemm_k<<<dim3(D / BN, (B * S) / BM), 256, 0, stream>>>(Ob, wo, bo, out);
}

// Round 3
// 457.718 us; speedup vs baseline: 1.9370x; 1.6249x over previous
//
#include <hip/hip_runtime.h>
#include <hip/hip_bf16.h>
#include <math.h>

#define B 2
#define S 2048
#define D 1024
#define H 16
#define HD 64
#define SCALE 0.125f
#define NEGBIG -1e30f

#define TQ 64   // queries per attention block
#define TK 64   // keys per chunk

typedef unsigned short u16;
typedef short bf16x8 __attribute__((ext_vector_type(8)));
typedef float f32x4  __attribute__((ext_vector_type(4)));

// ---------------- bf16 split helpers ----------------
__device__ __forceinline__ u16 f2bf(float f) {
    unsigned int u = __float_as_uint(f);
    unsigned int r = (u + 0x7fff + ((u >> 16) & 1)) >> 16;   // RNE
    return (u16)r;
}
__device__ __forceinline__ float bf2f(u16 s) {
    return __uint_as_float(((unsigned int)s) << 16);
}

__device__ __forceinline__ void gl_lds16(const void* g, void* l) {
    __builtin_amdgcn_global_load_lds(
        (const __attribute__((address_space(1))) unsigned int*)g,
        (__attribute__((address_space(3))) unsigned int*)l, 16, 0, 0);
}

// ---------------- fp32 -> (hi, lo) bf16 split ----------------
__global__ __launch_bounds__(256) void split_k(const float4* __restrict__ src,
                                               ushort4* __restrict__ hi,
                                               ushort4* __restrict__ lo, int n4) {
    int i = blockIdx.x * blockDim.x + threadIdx.x;
    if (i >= n4) return;
    float4 x = src[i];
    ushort4 h, l;
    h.x = f2bf(x.x); l.x = f2bf(x.x - bf2f(h.x));
    h.y = f2bf(x.y); l.y = f2bf(x.y - bf2f(h.y));
    h.z = f2bf(x.z); l.z = f2bf(x.z - bf2f(h.z));
    h.w = f2bf(x.w); l.w = f2bf(x.w - bf2f(h.w));
    hi[i] = h; lo[i] = l;
}

// ---------------- document span bounds (ids are sorted) ----------------
__global__ void docbounds_k(const int* __restrict__ doc, int* __restrict__ dstart,
                            int* __restrict__ dend) {
    int i = blockIdx.x * blockDim.x + threadIdx.x;
    if (i >= S) return;
    int v = doc[i];
    int lo = 0, hi = S;
    while (lo < hi) { int mid = (lo + hi) >> 1; if (doc[mid] < v) lo = mid + 1; else hi = mid; }
    dstart[i] = lo;
    lo = 0; hi = S;
    while (lo < hi) { int mid = (lo + hi) >> 1; if (doc[mid] <= v) lo = mid + 1; else hi = mid; }
    dend[i] = lo;
}

// ---------------- split-bf16 MFMA GEMM core ----------------
// C[m][n] = sum_k A[m][k] * Bw[n][k]  (A: M x 1024 row-major, Bw: N x 1024 row-major)
// via Ahi.Bhi + Ahi.Blo + Alo.Bhi on 16x16x32 bf16 MFMA.
// 128x128 tile, 4 waves in 2x2 (each 64x64 = 4x4 MFMA tiles), BK=32.
// LDS tiles 128 rows x 32 bf16, quad-slot XOR swizzle s(r) = (r>>1)&3 so both
// global_load_lds staging (wave-uniform base + lane*16) and ds_read_b128
// fragment loads are conflict-free (<=2-way).
__device__ __forceinline__ void gemm_core(
    const u16* __restrict__ Ahg, const u16* __restrict__ Alg,
    const u16* __restrict__ Bhg, const u16* __restrict__ Blg,
    int m0, int n0, u16* Ah, u16* Al, u16* Bh, u16* Bl, f32x4 acc[4][4])
{
    const int tid = threadIdx.x;
    const int w = tid >> 6;
    const int ln = tid & 63;
    const int wm = (w & 1) * 64, wn = (w >> 1) * 64;
    const int lc = ln & 15;
    const int quad = ln >> 4;
    const int srow = ln >> 2;
    const int slot = ln & 3;

    int a_off[4], b_off[4];
    #pragma unroll
    for (int t = 0; t < 4; t++) {
        int am = wm + t * 16 + lc;
        a_off[t] = am * 32 + ((quad ^ ((am >> 1) & 3)) * 8);
        int bn = wn + t * 16 + lc;
        b_off[t] = bn * 32 + ((quad ^ ((bn >> 1) & 3)) * 8);
    }

    for (int k0 = 0; k0 < 1024; k0 += 32) {
        #pragma unroll
        for (int half = 0; half < 2; half++) {
            int rl = half * 64 + w * 16 + srow;          // LDS row 0..127
            int q = slot ^ ((rl >> 1) & 3);              // content quad for this slot
            size_t ga = (size_t)(m0 + rl) * 1024 + k0 + q * 8;
            size_t gb = (size_t)(n0 + rl) * 1024 + k0 + q * 8;
            int lofs = (half * 64 + w * 16) * 32;        // wave-uniform LDS base
            gl_lds16(Ahg + ga, Ah + lofs);
            gl_lds16(Alg + ga, Al + lofs);
            gl_lds16(Bhg + gb, Bh + lofs);
            gl_lds16(Blg + gb, Bl + lofs);
        }
        __syncthreads();

        bf16x8 ah[4], al[4], bh[4], bl[4];
        #pragma unroll
        for (int t = 0; t < 4; t++) {
            ah[t] = *(const bf16x8*)&Ah[a_off[t]];
            al[t] = *(const bf16x8*)&Al[a_off[t]];
            bh[t] = *(const bf16x8*)&Bh[b_off[t]];
            bl[t] = *(const bf16x8*)&Bl[b_off[t]];
        }
        #pragma unroll
        for (int mt = 0; mt < 4; mt++)
            #pragma unroll
            for (int nt = 0; nt < 4; nt++) {
                acc[mt][nt] = __builtin_amdgcn_mfma_f32_16x16x32_bf16(al[mt], bh[nt], acc[mt][nt], 0, 0, 0);
                acc[mt][nt] = __builtin_amdgcn_mfma_f32_16x16x32_bf16(ah[mt], bl[nt], acc[mt][nt], 0, 0, 0);
                acc[mt][nt] = __builtin_amdgcn_mfma_f32_16x16x32_bf16(ah[mt], bh[nt], acc[mt][nt], 0, 0, 0);
            }
        __syncthreads();
    }
}

// ---------------- fused QKV projection (MFMA) ----------------
__global__ __launch_bounds__(256) void qkv_mfma_k(
    const u16* __restrict__ xh, const u16* __restrict__ xl,
    const u16* __restrict__ wh0, const u16* __restrict__ wl0,
    const u16* __restrict__ wh1, const u16* __restrict__ wl1,
    const u16* __restrict__ wh2, const u16* __restrict__ wl2,
    const float* __restrict__ bq, const float* __restrict__ bk,
    const float* __restrict__ bv,
    float* __restrict__ Qo, float* __restrict__ Ko, float* __restrict__ Vo)
{
    __shared__ u16 Ah[128 * 32], Al[128 * 32], Bh[128 * 32], Bl[128 * 32];
    const int which = blockIdx.z;
    const u16* Bhg = (which == 0) ? wh0 : (which == 1) ? wh1 : wh2;
    const u16* Blg = (which == 0) ? wl0 : (which == 1) ? wl1 : wl2;
    const float* bias = (which == 0) ? bq : (which == 1) ? bk : bv;
    float* Y = (which == 0) ? Qo : (which == 1) ? Ko : Vo;

    const int m0 = blockIdx.y * 128, n0 = blockIdx.x * 128;
    f32x4 acc[4][4];
    #pragma unroll
    for (int i = 0; i < 4; i++)
        #pragma unroll
        for (int j = 0; j < 4; j++) acc[i][j] = (f32x4){0.f, 0.f, 0.f, 0.f};

    gemm_core(xh, xl, Bhg, Blg, m0, n0, Ah, Al, Bh, Bl, acc);

    const int tid = threadIdx.x;
    const int w = tid >> 6, ln = tid & 63;
    const int wm = (w & 1) * 64, wn = (w >> 1) * 64;
    const int lc = ln & 15, quad = ln >> 4;

    #pragma unroll
    for (int nt = 0; nt < 4; nt++) {
        int col = n0 + wn + nt * 16 + lc;
        float bv_ = bias[col];
        int h = col >> 6, hd = col & 63;
        #pragma unroll
        for (int mt = 0; mt < 4; mt++) {
            #pragma unroll
            for (int r = 0; r < 4; r++) {
                int m = m0 + wm + mt * 16 + quad * 4 + r;
                int bb = m >> 11, s = m & (S - 1);
                Y[((size_t)((bb * H + h) * S) + s) * HD + hd] = acc[mt][nt][r] + bv_;
            }
        }
    }
}

// ---------------- output projection (MFMA) ----------------
__global__ __launch_bounds__(256) void out_mfma_k(
    const u16* __restrict__ oh, const u16* __restrict__ ol,
    const u16* __restrict__ wh, const u16* __restrict__ wl,
    const float* __restrict__ bias, float* __restrict__ Y)
{
    __shared__ u16 Ah[128 * 32], Al[128 * 32], Bh[128 * 32], Bl[128 * 32];
    const int m0 = blockIdx.y * 128, n0 = blockIdx.x * 128;
    f32x4 acc[4][4];
    #pragma unroll
    for (int i = 0; i < 4; i++)
        #pragma unroll
        for (int j = 0; j < 4; j++) acc[i][j] = (f32x4){0.f, 0.f, 0.f, 0.f};

    gemm_core(oh, ol, wh, wl, m0, n0, Ah, Al, Bh, Bl, acc);

    const int tid = threadIdx.x;
    const int w = tid >> 6, ln = tid & 63;
    const int wm = (w & 1) * 64, wn = (w >> 1) * 64;
    const int lc = ln & 15, quad = ln >> 4;

    #pragma unroll
    for (int nt = 0; nt < 4; nt++) {
        int col = n0 + wn + nt * 16 + lc;
        float bv_ = bias[col];
        #pragma unroll
        for (int mt = 0; mt < 4; mt++) {
            #pragma unroll
            for (int r = 0; r < 4; r++) {
                int m = m0 + wm + mt * 16 + quad * 4 + r;
                Y[(size_t)m * D + col] = acc[mt][nt][r] + bv_;
            }
        }
    }
}

// ---------------- block-diagonal flash attention, query-tiled ----------------
// Epilogue writes hi/lo bf16 split directly (A-operand of the out projection).
__global__ __launch_bounds__(256) void attn2_k(
    const float* __restrict__ Q, const float* __restrict__ K,
    const float* __restrict__ V, const int* __restrict__ dstart,
    const int* __restrict__ dend, u16* __restrict__ Ohi, u16* __restrict__ Olo)
{
    const int qt = blockIdx.x, h = blockIdx.y, b = blockIdx.z;
    const int q0 = qt * TQ;
    const size_t bh = ((size_t)b * H + h) * S;

    const int tid = threadIdx.x;
    const int lane = tid & 63;
    const int w = tid >> 6;

    __shared__ float qs[TQ][HD];
    __shared__ float Vs[TK][HD];
    __shared__ float Ps[4][16][TK];
    __shared__ int sstart[TQ], send[TQ];

    #pragma unroll
    for (int p = 0; p < 4; p++) {
        int e = tid + p * 256;
        int i = e >> 4, c = e & 15;
        float4 q4 = *(const float4*)(Q + (bh + q0 + i) * HD + c * 4);
        *(float4*)&qs[i][c * 4] =
            make_float4(q4.x * SCALE, q4.y * SCALE, q4.z * SCALE, q4.w * SCALE);
    }
    if (tid < TQ) {
        sstart[tid] = dstart[q0 + tid];
        send[tid]   = dend[q0 + tid];
    }
    __syncthreads();

    const int kstart = sstart[0];
    const int kend   = send[TQ - 1];

    float m_i[16], l_i[16], o_i[16], alpha[16];
    #pragma unroll
    for (int i = 0; i < 16; i++) { m_i[i] = NEGBIG; l_i[i] = 0.f; o_i[i] = 0.f; }

    for (int j0 = kstart; j0 < kend; j0 += TK) {
        #pragma unroll
        for (int p = 0; p < 4; p++) {
            int e = tid + p * 256;
            int j = e >> 4, c = e & 15;
            int jr = j0 + j; if (jr > S - 1) jr = S - 1;
            *(float4*)&Vs[j][c * 4] = *(const float4*)(V + (bh + jr) * HD + c * 4);
        }
        __syncthreads();

        int jme = j0 + lane;
        int jclamp = (jme > S - 1) ? (S - 1) : jme;
        float4 kreg[16];
        const float4* kp = (const float4*)(K + (bh + jclamp) * HD);
        #pragma unroll
        for (int c = 0; c < 16; c++) kreg[c] = kp[c];

        #pragma unroll
        for (int i = 0; i < 16; i++) {
            const int il = w * 16 + i;
            const float4* q4p = (const float4*)&qs[il][0];
            float s = 0.f;
            #pragma unroll
            for (int c = 0; c < 16; c++) {
                float4 q4 = q4p[c];
                s += q4.x * kreg[c].x + q4.y * kreg[c].y +
                     q4.z * kreg[c].z + q4.w * kreg[c].w;
            }
            const int st = sstart[il], en = send[il];
            const bool valid = (jme >= st) && (jme < en);
            float sv = valid ? s : NEGBIG;

            float wmx = sv;
            #pragma unroll
            for (int off = 32; off >= 1; off >>= 1) wmx = fmaxf(wmx, __shfl_xor(wmx, off, 64));
            float m_new = fmaxf(m_i[i], wmx);
            alpha[i] = __expf(m_i[i] - m_new);
            float p = valid ? __expf(sv - m_new) : 0.f;
            float psum = p;
            #pragma unroll
            for (int off = 32; off >= 1; off >>= 1) psum += __shfl_xor(psum, off, 64);
            l_i[i] = l_i[i] * alpha[i] + psum;
            m_i[i] = m_new;
            o_i[i] *= alpha[i];
            Ps[w][i][lane] = p;
        }

        #pragma unroll 4
        for (int jj = 0; jj < TK; jj += 4) {
            float v0 = Vs[jj + 0][lane];
            float v1 = Vs[jj + 1][lane];
            float v2 = Vs[jj + 2][lane];
            float v3 = Vs[jj + 3][lane];
            #pragma unroll
            for (int i = 0; i < 16; i++) {
                float4 p4 = *(const float4*)&Ps[w][i][jj];
                o_i[i] = fmaf(p4.x, v0, fmaf(p4.y, v1, fmaf(p4.z, v2, fmaf(p4.w, v3, o_i[i]))));
            }
        }
        __syncthreads();
    }

    #pragma unroll
    for (int i = 0; i < 16; i++) {
        const int il = w * 16 + i;
        const int iq = q0 + il;
        float val = o_i[i] / l_i[i];
        size_t idx = ((size_t)(b * S + iq) * H + h) * HD + lane;
        u16 hb = f2bf(val);
        Ohi[idx] = hb;
        Olo[idx] = f2bf(val - bf2f(hb));
    }
}

extern "C" void kernel_launch(void* const* d_in, const int* in_sizes, int n_in,
                              void* d_out, int out_size, void* d_ws, size_t ws_size,
                              hipStream_t stream) {
    const float* hs = (const float*)d_in[0];
    const float* wq = (const float*)d_in[1];
    const float* bq = (const float*)d_in[2];
    const float* wk = (const float*)d_in[3];
    const float* bk = (const float*)d_in[4];
    const float* wv = (const float*)d_in[5];
    const float* bv = (const float*)d_in[6];
    const float* wo = (const float*)d_in[7];
    const float* bo = (const float*)d_in[8];
    const int*  doc = (const int*)d_in[9];
    float* out = (float*)d_out;

    const size_t NE = (size_t)B * S * D;       // 4,194,304
    const size_t NW = (size_t)D * D;           // 1,048,576
    float* Qb = (float*)d_ws;
    float* Kb = Qb + NE;
    float* Vb = Kb + NE;
    u16* xh = (u16*)(Vb + NE);                 // aliased as Ohi after qkv GEMM
    u16* xl = xh + NE;                         // aliased as Olo
    u16* wqh = xl + NE;  u16* wql = wqh + NW;
    u16* wkh = wql + NW; u16* wkl = wkh + NW;
    u16* wvh = wkl + NW; u16* wvl = wvh + NW;
    u16* woh = wvl + NW; u16* wol = woh + NW;
    int* dstart = (int*)(wol + NW);
    int* dend = dstart + S;

    docbounds_k<<<(S + 255) / 256, 256, 0, stream>>>(doc, dstart, dend);
    split_k<<<(int)(NE / 4 / 256), 256, 0, stream>>>((const float4*)hs, (ushort4*)xh, (ushort4*)xl, (int)(NE / 4));
    split_k<<<(int)(NW / 4 / 256), 256, 0, stream>>>((const float4*)wq, (ushort4*)wqh, (ushort4*)wql, (int)(NW / 4));
    split_k<<<(int)(NW / 4 / 256), 256, 0, stream>>>((const float4*)wk, (ushort4*)wkh, (ushort4*)wkl, (int)(NW / 4));
    split_k<<<(int)(NW / 4 / 256), 256, 0, stream>>>((const float4*)wv, (ushort4*)wvh, (ushort4*)wvl, (int)(NW / 4));
    split_k<<<(int)(NW / 4 / 256), 256, 0, stream>>>((const float4*)wo, (ushort4*)woh, (ushort4*)wol, (int)(NW / 4));

    qkv_mfma_k<<<dim3(D / 128, (B * S) / 128, 3), 256, 0, stream>>>(
        xh, xl, wqh, wql, wkh, wkl, wvh, wvl, bq, bk, bv, Qb, Kb, Vb);
    attn2_k<<<dim3(S / TQ, H, B), 256, 0, stream>>>(Qb, Kb, Vb, dstart, dend, xh, xl);
    out_mfma_k<<<dim3(D / 128, (B * S) / 128), 256, 0, stream>>>(xh, xl, woh, wol, bo, out);
}

// Round 4
// 333.030 us; speedup vs baseline: 2.6622x; 1.3744x over previous
//
#include <hip/hip_runtime.h>
#include <hip/hip_bf16.h>
#include <math.h>

#define B 2
#define S 2048
#define D 1024
#define H 16
#define HD 64
#define SCALE 0.125f
#define NEGBIG -1e30f
#define TQ 64

typedef unsigned short u16;
typedef short bf16x8 __attribute__((ext_vector_type(8)));
typedef float f32x4  __attribute__((ext_vector_type(4)));

// ---------------- bf16 split helpers ----------------
__device__ __forceinline__ u16 f2bf(float f) {
    unsigned int u = __float_as_uint(f);
    unsigned int r = (u + 0x7fff + ((u >> 16) & 1)) >> 16;   // RNE
    return (u16)r;
}
__device__ __forceinline__ float bf2f(u16 s) {
    return __uint_as_float(((unsigned int)s) << 16);
}

__device__ __forceinline__ void gl_lds16(const void* g, void* l) {
    __builtin_amdgcn_global_load_lds(
        (const __attribute__((address_space(1))) unsigned int*)g,
        (__attribute__((address_space(3))) unsigned int*)l, 16, 0, 0);
}

// ---------------- fp32 -> (hi, lo) bf16 split ----------------
__global__ __launch_bounds__(256) void split_k(const float4* __restrict__ src,
                                               ushort4* __restrict__ hi,
                                               ushort4* __restrict__ lo, int n4) {
    int i = blockIdx.x * blockDim.x + threadIdx.x;
    if (i >= n4) return;
    float4 x = src[i];
    ushort4 h, l;
    h.x = f2bf(x.x); l.x = f2bf(x.x - bf2f(h.x));
    h.y = f2bf(x.y); l.y = f2bf(x.y - bf2f(h.y));
    h.z = f2bf(x.z); l.z = f2bf(x.z - bf2f(h.z));
    h.w = f2bf(x.w); l.w = f2bf(x.w - bf2f(h.w));
    hi[i] = h; lo[i] = l;
}

// ---------------- document span bounds (ids are sorted) ----------------
__global__ void docbounds_k(const int* __restrict__ doc, int* __restrict__ dstart,
                            int* __restrict__ dend) {
    int i = blockIdx.x * blockDim.x + threadIdx.x;
    if (i >= S) return;
    int v = doc[i];
    int lo = 0, hi = S;
    while (lo < hi) { int mid = (lo + hi) >> 1; if (doc[mid] < v) lo = mid + 1; else hi = mid; }
    dstart[i] = lo;
    lo = 0; hi = S;
    while (lo < hi) { int mid = (lo + hi) >> 1; if (doc[mid] <= v) lo = mid + 1; else hi = mid; }
    dend[i] = lo;
}

// ---------------- split-bf16 MFMA GEMM core (unchanged, 0 conflicts) ----------------
__device__ __forceinline__ void gemm_core(
    const u16* __restrict__ Ahg, const u16* __restrict__ Alg,
    const u16* __restrict__ Bhg, const u16* __restrict__ Blg,
    int m0, int n0, u16* Ah, u16* Al, u16* Bh, u16* Bl, f32x4 acc[4][4])
{
    const int tid = threadIdx.x;
    const int w = tid >> 6;
    const int ln = tid & 63;
    const int wm = (w & 1) * 64, wn = (w >> 1) * 64;
    const int lc = ln & 15;
    const int quad = ln >> 4;
    const int srow = ln >> 2;
    const int slot = ln & 3;

    int a_off[4], b_off[4];
    #pragma unroll
    for (int t = 0; t < 4; t++) {
        int am = wm + t * 16 + lc;
        a_off[t] = am * 32 + ((quad ^ ((am >> 1) & 3)) * 8);
        int bn = wn + t * 16 + lc;
        b_off[t] = bn * 32 + ((quad ^ ((bn >> 1) & 3)) * 8);
    }

    for (int k0 = 0; k0 < 1024; k0 += 32) {
        #pragma unroll
        for (int half = 0; half < 2; half++) {
            int rl = half * 64 + w * 16 + srow;
            int q = slot ^ ((rl >> 1) & 3);
            size_t ga = (size_t)(m0 + rl) * 1024 + k0 + q * 8;
            size_t gb = (size_t)(n0 + rl) * 1024 + k0 + q * 8;
            int lofs = (half * 64 + w * 16) * 32;
            gl_lds16(Ahg + ga, Ah + lofs);
            gl_lds16(Alg + ga, Al + lofs);
            gl_lds16(Bhg + gb, Bh + lofs);
            gl_lds16(Blg + gb, Bl + lofs);
        }
        __syncthreads();

        bf16x8 ah[4], al[4], bh[4], bl[4];
        #pragma unroll
        for (int t = 0; t < 4; t++) {
            ah[t] = *(const bf16x8*)&Ah[a_off[t]];
            al[t] = *(const bf16x8*)&Al[a_off[t]];
            bh[t] = *(const bf16x8*)&Bh[b_off[t]];
            bl[t] = *(const bf16x8*)&Bl[b_off[t]];
        }
        #pragma unroll
        for (int mt = 0; mt < 4; mt++)
            #pragma unroll
            for (int nt = 0; nt < 4; nt++) {
                acc[mt][nt] = __builtin_amdgcn_mfma_f32_16x16x32_bf16(al[mt], bh[nt], acc[mt][nt], 0, 0, 0);
                acc[mt][nt] = __builtin_amdgcn_mfma_f32_16x16x32_bf16(ah[mt], bl[nt], acc[mt][nt], 0, 0, 0);
                acc[mt][nt] = __builtin_amdgcn_mfma_f32_16x16x32_bf16(ah[mt], bh[nt], acc[mt][nt], 0, 0, 0);
            }
        __syncthreads();
    }
}

// ---------------- fused QKV projection (MFMA) -> split bf16 Q,K,V^T ----------------
__global__ __launch_bounds__(256) void qkv_mfma_k(
    const u16* __restrict__ xh, const u16* __restrict__ xl,
    const u16* __restrict__ wh0, const u16* __restrict__ wl0,
    const u16* __restrict__ wh1, const u16* __restrict__ wl1,
    const u16* __restrict__ wh2, const u16* __restrict__ wl2,
    const float* __restrict__ bq, const float* __restrict__ bk,
    const float* __restrict__ bv,
    u16* __restrict__ Qh, u16* __restrict__ Ql,
    u16* __restrict__ Kh, u16* __restrict__ Kl,
    u16* __restrict__ Vth, u16* __restrict__ Vtl)
{
    __shared__ u16 Ah[128 * 32], Al[128 * 32], Bh[128 * 32], Bl[128 * 32];
    const int which = blockIdx.z;
    const u16* Bhg = (which == 0) ? wh0 : (which == 1) ? wh1 : wh2;
    const u16* Blg = (which == 0) ? wl0 : (which == 1) ? wl1 : wl2;
    const float* bias = (which == 0) ? bq : (which == 1) ? bk : bv;

    const int m0 = blockIdx.y * 128, n0 = blockIdx.x * 128;
    f32x4 acc[4][4];
    #pragma unroll
    for (int i = 0; i < 4; i++)
        #pragma unroll
        for (int j = 0; j < 4; j++) acc[i][j] = (f32x4){0.f, 0.f, 0.f, 0.f};

    gemm_core(xh, xl, Bhg, Blg, m0, n0, Ah, Al, Bh, Bl, acc);

    const int tid = threadIdx.x;
    const int w = tid >> 6, ln = tid & 63;
    const int wm = (w & 1) * 64, wn = (w >> 1) * 64;
    const int lc = ln & 15, quad = ln >> 4;

    u16* Yh = (which == 0) ? Qh : (which == 1) ? Kh : Vth;
    u16* Yl = (which == 0) ? Ql : (which == 1) ? Kl : Vtl;

    #pragma unroll
    for (int nt = 0; nt < 4; nt++) {
        int col = n0 + wn + nt * 16 + lc;
        float bv_ = bias[col];
        int h = col >> 6, hd = col & 63;
        #pragma unroll
        for (int mt = 0; mt < 4; mt++) {
            #pragma unroll
            for (int r = 0; r < 4; r++) {
                int m = m0 + wm + mt * 16 + quad * 4 + r;
                int bb = m >> 11, s = m & (S - 1);
                float val = acc[mt][nt][r] + bv_;
                u16 hb = f2bf(val);
                u16 lb = f2bf(val - bf2f(hb));
                size_t idx;
                if (which < 2) idx = (((size_t)(bb * H + h) * S) + s) * HD + hd;
                else           idx = (((size_t)(bb * H + h) * HD) + hd) * S + s;
                Yh[idx] = hb;
                Yl[idx] = lb;
            }
        }
    }
}

// ---------------- output projection (MFMA) ----------------
__global__ __launch_bounds__(256) void out_mfma_k(
    const u16* __restrict__ oh, const u16* __restrict__ ol,
    const u16* __restrict__ wh, const u16* __restrict__ wl,
    const float* __restrict__ bias, float* __restrict__ Y)
{
    __shared__ u16 Ah[128 * 32], Al[128 * 32], Bh[128 * 32], Bl[128 * 32];
    const int m0 = blockIdx.y * 128, n0 = blockIdx.x * 128;
    f32x4 acc[4][4];
    #pragma unroll
    for (int i = 0; i < 4; i++)
        #pragma unroll
        for (int j = 0; j < 4; j++) acc[i][j] = (f32x4){0.f, 0.f, 0.f, 0.f};

    gemm_core(oh, ol, wh, wl, m0, n0, Ah, Al, Bh, Bl, acc);

    const int tid = threadIdx.x;
    const int w = tid >> 6, ln = tid & 63;
    const int wm = (w & 1) * 64, wn = (w >> 1) * 64;
    const int lc = ln & 15, quad = ln >> 4;

    #pragma unroll
    for (int nt = 0; nt < 4; nt++) {
        int col = n0 + wn + nt * 16 + lc;
        float bv_ = bias[col];
        #pragma unroll
        for (int mt = 0; mt < 4; mt++) {
            #pragma unroll
            for (int r = 0; r < 4; r++) {
                int m = m0 + wm + mt * 16 + quad * 4 + r;
                Y[(size_t)m * D + col] = acc[mt][nt][r] + bv_;
            }
        }
    }
}

// ---------------- MFMA block-diagonal flash attention ----------------
// 256 threads, 4 waves; wave w owns queries q0+w*16 .. +15. Key chunks of 64,
// aligned to 64. Scores & PV on 16x16x32 bf16 MFMA with hi/lo split.
__global__ __launch_bounds__(256) void attn3_k(
    const u16* __restrict__ Qh, const u16* __restrict__ Ql,
    const u16* __restrict__ Kh, const u16* __restrict__ Kl,
    const u16* __restrict__ Vth, const u16* __restrict__ Vtl,
    const int* __restrict__ dstart, const int* __restrict__ dend,
    u16* __restrict__ Ohi, u16* __restrict__ Olo)
{
    const int qt = blockIdx.x, h = blockIdx.y, b = blockIdx.z;
    const int q0 = qt * TQ;
    const size_t bh  = ((size_t)b * H + h) * S;    // Q/K row base
    const size_t bhv = ((size_t)b * H + h) * HD;   // Vt dim-row base

    const int tid = threadIdx.x;
    const int w = tid >> 6, ln = tid & 63;
    const int lc = ln & 15, quad = ln >> 4;

    __shared__ u16 VtHs[64 * 64], VtLs[64 * 64];   // [dim][key-octet swizzled]
    __shared__ float Ps[4][16 * 64];               // per-wave P, octet-swizzled
    __shared__ int sb[TQ], se[TQ];

    if (tid < TQ) { sb[tid] = dstart[q0 + tid]; se[tid] = dend[q0 + tid]; }

    // Q fragments (A-layout), loaded once: A[m=lc][k=ks*32+quad*8+j]
    const size_t qrow = bh + q0 + w * 16 + lc;
    bf16x8 qfh[2], qfl[2];
    #pragma unroll
    for (int ks = 0; ks < 2; ks++) {
        qfh[ks] = *(const bf16x8*)(Qh + qrow * HD + ks * 32 + quad * 8);
        qfl[ks] = *(const bf16x8*)(Ql + qrow * HD + ks * 32 + quad * 8);
    }
    __syncthreads();

    int row_st[4], row_en[4];
    #pragma unroll
    for (int r = 0; r < 4; r++) {
        row_st[r] = sb[w * 16 + quad * 4 + r];
        row_en[r] = se[w * 16 + quad * 4 + r];
    }
    const int kstart = sb[0] & ~63;
    const int kend   = se[TQ - 1];

    f32x4 o[4];
    #pragma unroll
    for (int nt = 0; nt < 4; nt++) o[nt] = (f32x4){0.f, 0.f, 0.f, 0.f};
    f32x4 m_i = (f32x4){NEGBIG, NEGBIG, NEGBIG, NEGBIG};
    f32x4 l_i = (f32x4){0.f, 0.f, 0.f, 0.f};

    for (int j0 = kstart; j0 < kend; j0 += 64) {
        __syncthreads();   // previous chunk's Vt reads done
        // ---- stage V^T chunk into LDS (hi/lo), octet-XOR swizzle ----
        #pragma unroll
        for (int p = 0; p < 2; p++) {
            int idx = tid + p * 256;          // 0..511
            int dim = idx >> 3, g = idx & 7;
            int slot = g ^ (dim & 7);
            size_t gsrc = (bhv + dim) * S + j0 + g * 8;
            *(uint4*)&VtHs[dim * 64 + slot * 8] = *(const uint4*)(Vth + gsrc);
            *(uint4*)&VtLs[dim * 64 + slot * 8] = *(const uint4*)(Vtl + gsrc);
        }

        // ---- K fragments from global (B-layout): key=j0+t*16+lc, dims ks*32+quad*8 ----
        bf16x8 kfh[4][2], kfl[4][2];
        #pragma unroll
        for (int t = 0; t < 4; t++) {
            size_t krow = (bh + j0 + t * 16 + lc) * HD;
            #pragma unroll
            for (int ks = 0; ks < 2; ks++) {
                kfh[t][ks] = *(const bf16x8*)(Kh + krow + ks * 32 + quad * 8);
                kfl[t][ks] = *(const bf16x8*)(Kl + krow + ks * 32 + quad * 8);
            }
        }
        __syncthreads();   // Vt staged

        // ---- scores: S[row=quad*4+r][key=t*16+lc] ----
        f32x4 sc[4];
        #pragma unroll
        for (int t = 0; t < 4; t++) {
            f32x4 a = (f32x4){0.f, 0.f, 0.f, 0.f};
            #pragma unroll
            for (int ks = 0; ks < 2; ks++) {
                a = __builtin_amdgcn_mfma_f32_16x16x32_bf16(qfl[ks], kfh[t][ks], a, 0, 0, 0);
                a = __builtin_amdgcn_mfma_f32_16x16x32_bf16(qfh[ks], kfl[t][ks], a, 0, 0, 0);
                a = __builtin_amdgcn_mfma_f32_16x16x32_bf16(qfh[ks], kfh[t][ks], a, 0, 0, 0);
            }
            int key = j0 + t * 16 + lc;
            #pragma unroll
            for (int r = 0; r < 4; r++) {
                float sv = a[r] * SCALE;
                bool valid = (key >= row_st[r]) && (key < row_en[r]);
                sc[t][r] = valid ? sv : NEGBIG;
            }
        }

        // ---- online softmax, all 16 rows at once ----
        f32x4 mx = sc[0];
        #pragma unroll
        for (int t = 1; t < 4; t++)
            #pragma unroll
            for (int r = 0; r < 4; r++) mx[r] = fmaxf(mx[r], sc[t][r]);
        #pragma unroll
        for (int off = 1; off <= 8; off <<= 1)
            #pragma unroll
            for (int r = 0; r < 4; r++) mx[r] = fmaxf(mx[r], __shfl_xor(mx[r], off, 64));

        f32x4 m_new, alpha;
        #pragma unroll
        for (int r = 0; r < 4; r++) {
            m_new[r] = fmaxf(m_i[r], mx[r]);
            alpha[r] = __expf(m_i[r] - m_new[r]);
        }

        f32x4 psum = (f32x4){0.f, 0.f, 0.f, 0.f};
        f32x4 pv[4];
        #pragma unroll
        for (int t = 0; t < 4; t++) {
            #pragma unroll
            for (int r = 0; r < 4; r++) {
                float p = __expf(sc[t][r] - m_new[r]);
                p = (sc[t][r] < -5e29f) ? 0.f : p;
                pv[t][r] = p;
                psum[r] += p;
            }
        }
        #pragma unroll
        for (int off = 1; off <= 8; off <<= 1)
            #pragma unroll
            for (int r = 0; r < 4; r++) psum[r] += __shfl_xor(psum[r], off, 64);

        #pragma unroll
        for (int r = 0; r < 4; r++) {
            l_i[r] = l_i[r] * alpha[r] + psum[r];
            m_i[r] = m_new[r];
        }
        #pragma unroll
        for (int nt = 0; nt < 4; nt++)
            #pragma unroll
            for (int r = 0; r < 4; r++) o[nt][r] *= alpha[r];

        // ---- write P to LDS (C-layout -> swizzled [q][key]) ----
        #pragma unroll
        for (int t = 0; t < 4; t++) {
            int g = 2 * t + (lc >> 3);
            #pragma unroll
            for (int r = 0; r < 4; r++) {
                int q = quad * 4 + r;
                Ps[w][q * 64 + ((g ^ (q & 7)) * 8) + (lc & 7)] = pv[t][r];
            }
        }
        __syncthreads();   // P visible (cross-lane within wave; waves aligned)

        // ---- PV: O += P * V ----
        #pragma unroll
        for (int ks = 0; ks < 2; ks++) {
            // P A-frag: A[m=lc][k=ks*32+quad*8+j]
            int gp = ks * 4 + quad;
            const float* prow = &Ps[w][lc * 64 + ((gp ^ (lc & 7)) * 8)];
            bf16x8 ph, pl;
            #pragma unroll
            for (int j = 0; j < 8; j++) {
                float f = prow[j];
                u16 hb = f2bf(f);
                ph[j] = (short)hb;
                pl[j] = (short)f2bf(f - bf2f(hb));
            }
            #pragma unroll
            for (int nt = 0; nt < 4; nt++) {
                int dim = nt * 16 + lc;
                int slot = gp ^ (dim & 7);
                bf16x8 vh = *(const bf16x8*)&VtHs[dim * 64 + slot * 8];
                bf16x8 vl = *(const bf16x8*)&VtLs[dim * 64 + slot * 8];
                o[nt] = __builtin_amdgcn_mfma_f32_16x16x32_bf16(pl, vh, o[nt], 0, 0, 0);
                o[nt] = __builtin_amdgcn_mfma_f32_16x16x32_bf16(ph, vl, o[nt], 0, 0, 0);
                o[nt] = __builtin_amdgcn_mfma_f32_16x16x32_bf16(ph, vh, o[nt], 0, 0, 0);
            }
        }
    }

    // ---- epilogue: O[(b*S+q)*D + h*64 + dim], hi/lo split for out-proj ----
    f32x4 inv;
    #pragma unroll
    for (int r = 0; r < 4; r++) inv[r] = 1.f / l_i[r];
    #pragma unroll
    for (int nt = 0; nt < 4; nt++) {
        int dim = nt * 16 + lc;
        #pragma unroll
        for (int r = 0; r < 4; r++) {
            int q = q0 + w * 16 + quad * 4 + r;
            float val = o[nt][r] * inv[r];
            size_t idx = ((size_t)(b * S + q)) * D + h * 64 + dim;
            u16 hb = f2bf(val);
            Ohi[idx] = hb;
            Olo[idx] = f2bf(val - bf2f(hb));
        }
    }
}

extern "C" void kernel_launch(void* const* d_in, const int* in_sizes, int n_in,
                              void* d_out, int out_size, void* d_ws, size_t ws_size,
                              hipStream_t stream) {
    const float* hs = (const float*)d_in[0];
    const float* wq = (const float*)d_in[1];
    const float* bq = (const float*)d_in[2];
    const float* wk = (const float*)d_in[3];
    const float* bk = (const float*)d_in[4];
    const float* wv = (const float*)d_in[5];
    const float* bv = (const float*)d_in[6];
    const float* wo = (const float*)d_in[7];
    const float* bo = (const float*)d_in[8];
    const int*  doc = (const int*)d_in[9];
    float* out = (float*)d_out;

    const size_t NE = (size_t)B * S * D;       // 4,194,304
    const size_t NW = (size_t)D * D;           // 1,048,576
    u16* xh  = (u16*)d_ws;   u16* xl  = xh + NE;   // hidden split; reused as Ohi/Olo
    u16* Qhb = xl + NE;      u16* Qlb = Qhb + NE;
    u16* Khb = Qlb + NE;     u16* Klb = Khb + NE;
    u16* Vth = Klb + NE;     u16* Vtl = Vth + NE;
    u16* wqh = Vtl + NE;  u16* wql = wqh + NW;
    u16* wkh = wql + NW;  u16* wkl = wkh + NW;
    u16* wvh = wkl + NW;  u16* wvl = wvh + NW;
    u16* woh = wvl + NW;  u16* wol = woh + NW;
    int* dstart = (int*)(wol + NW);
    int* dend = dstart + S;

    docbounds_k<<<(S + 255) / 256, 256, 0, stream>>>(doc, dstart, dend);
    split_k<<<(int)(NE / 4 / 256), 256, 0, stream>>>((const float4*)hs, (ushort4*)xh, (ushort4*)xl, (int)(NE / 4));
    split_k<<<(int)(NW / 4 / 256), 256, 0, stream>>>((const float4*)wq, (ushort4*)wqh, (ushort4*)wql, (int)(NW / 4));
    split_k<<<(int)(NW / 4 / 256), 256, 0, stream>>>((const float4*)wk, (ushort4*)wkh, (ushort4*)wkl, (int)(NW / 4));
    split_k<<<(int)(NW / 4 / 256), 256, 0, stream>>>((const float4*)wv, (ushort4*)wvh, (ushort4*)wvl, (int)(NW / 4));
    split_k<<<(int)(NW / 4 / 256), 256, 0, stream>>>((const float4*)wo, (ushort4*)woh, (ushort4*)wol, (int)(NW / 4));

    qkv_mfma_k<<<dim3(D / 128, (B * S) / 128, 3), 256, 0, stream>>>(
        xh, xl, wqh, wql, wkh, wkl, wvh, wvl, bq, bk, bv,
        Qhb, Qlb, Khb, Klb, Vth, Vtl);
    attn3_k<<<dim3(S / TQ, H, B), 256, 0, stream>>>(
        Qhb, Qlb, Khb, Klb, Vth, Vtl, dstart, dend, xh, xl);
    out_mfma_k<<<dim3(D / 128, (B * S) / 128), 256, 0, stream>>>(xh, xl, woh, wol, bo, out);
}

// Round 5
// 270.627 us; speedup vs baseline: 3.2760x; 1.2306x over previous
//
#include <hip/hip_runtime.h>
#include <hip/hip_bf16.h>
#include <math.h>

#define B 2
#define S 2048
#define D 1024
#define H 16
#define HD 64
#define SCALE 0.125f
#define NEGBIG -1e30f
#define TQ 64

typedef _Float16 f16;
typedef _Float16 f16x8 __attribute__((ext_vector_type(8)));
typedef _Float16 f16x4 __attribute__((ext_vector_type(4)));
typedef float f32x4  __attribute__((ext_vector_type(4)));

__device__ __forceinline__ void gl_lds16(const void* g, void* l) {
    __builtin_amdgcn_global_load_lds(
        (const __attribute__((address_space(1))) unsigned int*)g,
        (__attribute__((address_space(3))) unsigned int*)l, 16, 0, 0);
}

// ---------------- fp32 -> (hi, lo) fp16 split (8 elem/thread) ----------------
__global__ __launch_bounds__(256) void split2_k(const float4* __restrict__ src,
                                                f16x8* __restrict__ hi,
                                                f16x8* __restrict__ lo, int n8) {
    int i = blockIdx.x * blockDim.x + threadIdx.x;
    if (i >= n8) return;
    float4 a = src[2 * i], b = src[2 * i + 1];
    float v[8] = {a.x, a.y, a.z, a.w, b.x, b.y, b.z, b.w};
    f16x8 h, l;
    #pragma unroll
    for (int j = 0; j < 8; j++) {
        f16 hh = (f16)v[j];
        h[j] = hh;
        l[j] = (f16)(v[j] - (float)hh);
    }
    hi[i] = h; lo[i] = l;
}

// ---------------- fp32 -> fp16 convert (hi only, for weights) ----------------
__global__ __launch_bounds__(256) void conv_k(const float4* __restrict__ src,
                                              f16x8* __restrict__ dst, int n8) {
    int i = blockIdx.x * blockDim.x + threadIdx.x;
    if (i >= n8) return;
    float4 a = src[2 * i], b = src[2 * i + 1];
    f16x8 h;
    h[0] = (f16)a.x; h[1] = (f16)a.y; h[2] = (f16)a.z; h[3] = (f16)a.w;
    h[4] = (f16)b.x; h[5] = (f16)b.y; h[6] = (f16)b.z; h[7] = (f16)b.w;
    dst[i] = h;
}

// ---------------- document span bounds (ids are sorted) ----------------
__global__ void docbounds_k(const int* __restrict__ doc, int* __restrict__ dstart,
                            int* __restrict__ dend) {
    int i = blockIdx.x * blockDim.x + threadIdx.x;
    if (i >= S) return;
    int v = doc[i];
    int lo = 0, hi = S;
    while (lo < hi) { int mid = (lo + hi) >> 1; if (doc[mid] < v) lo = mid + 1; else hi = mid; }
    dstart[i] = lo;
    lo = 0; hi = S;
    while (lo < hi) { int mid = (lo + hi) >> 1; if (doc[mid] <= v) lo = mid + 1; else hi = mid; }
    dend[i] = lo;
}

// ---------------- 2-term fp16 MFMA GEMM core ----------------
// C[m][n] = sum_k A[m][k] * Bw[n][k], A exact via hi+lo fp16, B fp16 (hi).
// 128x128 tile, 4 waves 2x2, BK=32, quad-XOR swizzled LDS, 0-conflict staging.
__device__ __forceinline__ void gemm_core(
    const f16* __restrict__ Ahg, const f16* __restrict__ Alg,
    const f16* __restrict__ Bhg,
    int m0, int n0, f16* Ah, f16* Al, f16* Bh, f32x4 acc[4][4])
{
    const int tid = threadIdx.x;
    const int w = tid >> 6;
    const int ln = tid & 63;
    const int wm = (w & 1) * 64, wn = (w >> 1) * 64;
    const int lc = ln & 15;
    const int quad = ln >> 4;
    const int srow = ln >> 2;
    const int slot = ln & 3;

    int a_off[4], b_off[4];
    #pragma unroll
    for (int t = 0; t < 4; t++) {
        int am = wm + t * 16 + lc;
        a_off[t] = am * 32 + ((quad ^ ((am >> 1) & 3)) * 8);
        int bn = wn + t * 16 + lc;
        b_off[t] = bn * 32 + ((quad ^ ((bn >> 1) & 3)) * 8);
    }

    for (int k0 = 0; k0 < 1024; k0 += 32) {
        #pragma unroll
        for (int half = 0; half < 2; half++) {
            int rl = half * 64 + w * 16 + srow;
            int q = slot ^ ((rl >> 1) & 3);
            size_t ga = (size_t)(m0 + rl) * 1024 + k0 + q * 8;
            size_t gb = (size_t)(n0 + rl) * 1024 + k0 + q * 8;
            int lofs = (half * 64 + w * 16) * 32;
            gl_lds16(Ahg + ga, Ah + lofs);
            gl_lds16(Alg + ga, Al + lofs);
            gl_lds16(Bhg + gb, Bh + lofs);
        }
        __syncthreads();

        f16x8 ah[4], al[4], bh[4];
        #pragma unroll
        for (int t = 0; t < 4; t++) {
            ah[t] = *(const f16x8*)&Ah[a_off[t]];
            al[t] = *(const f16x8*)&Al[a_off[t]];
            bh[t] = *(const f16x8*)&Bh[b_off[t]];
        }
        #pragma unroll
        for (int mt = 0; mt < 4; mt++)
            #pragma unroll
            for (int nt = 0; nt < 4; nt++) {
                acc[mt][nt] = __builtin_amdgcn_mfma_f32_16x16x32_f16(al[mt], bh[nt], acc[mt][nt], 0, 0, 0);
                acc[mt][nt] = __builtin_amdgcn_mfma_f32_16x16x32_f16(ah[mt], bh[nt], acc[mt][nt], 0, 0, 0);
            }
        __syncthreads();
    }
}

// ---------------- fused QKV projection (MFMA) ----------------
// Q: (b,h,s,hd) hi+lo, pre-scaled by SCALE. K: (b,h,s,hd) hi only.
// V: (b,h,hd,s) hi only, coalesced via LDS transpose.
__global__ __launch_bounds__(256) void qkv_mfma_k(
    const f16* __restrict__ xh, const f16* __restrict__ xl,
    const f16* __restrict__ wqh, const f16* __restrict__ wkh,
    const f16* __restrict__ wvh,
    const float* __restrict__ bq, const float* __restrict__ bk,
    const float* __restrict__ bv,
    f16* __restrict__ Qh, f16* __restrict__ Ql,
    f16* __restrict__ Kh, f16* __restrict__ Vth)
{
    __shared__ union {
        struct { f16 Ah[128 * 32]; f16 Al[128 * 32]; f16 Bh[128 * 32]; } s;
        f16 tr[128 * 136];     // [col][m] transpose pad=8
    } lds;

    const int which = blockIdx.z;
    const f16* Bhg = (which == 0) ? wqh : (which == 1) ? wkh : wvh;
    const float* bias = (which == 0) ? bq : (which == 1) ? bk : bv;

    const int m0 = blockIdx.y * 128, n0 = blockIdx.x * 128;
    f32x4 acc[4][4];
    #pragma unroll
    for (int i = 0; i < 4; i++)
        #pragma unroll
        for (int j = 0; j < 4; j++) acc[i][j] = (f32x4){0.f, 0.f, 0.f, 0.f};

    gemm_core(xh, xl, Bhg, m0, n0, lds.s.Ah, lds.s.Al, lds.s.Bh, acc);

    const int tid = threadIdx.x;
    const int w = tid >> 6, ln = tid & 63;
    const int wm = (w & 1) * 64, wn = (w >> 1) * 64;
    const int lc = ln & 15, quad = ln >> 4;

    if (which < 2) {
        #pragma unroll
        for (int nt = 0; nt < 4; nt++) {
            int col = n0 + wn + nt * 16 + lc;
            float bv_ = bias[col];
            int h = col >> 6, hd = col & 63;
            #pragma unroll
            for (int mt = 0; mt < 4; mt++) {
                #pragma unroll
                for (int r = 0; r < 4; r++) {
                    int m = m0 + wm + mt * 16 + quad * 4 + r;
                    int bb = m >> 11, s = m & (S - 1);
                    float val = acc[mt][nt][r] + bv_;
                    size_t idx = (((size_t)(bb * H + h) * S) + s) * HD + hd;
                    if (which == 0) {
                        val *= SCALE;                  // fold softmax scale into Q
                        f16 hh = (f16)val;
                        Qh[idx] = hh;
                        Ql[idx] = (f16)(val - (float)hh);
                    } else {
                        Kh[idx] = (f16)val;
                    }
                }
            }
        }
    } else {
        // V: transpose in LDS, then coalesced stores along s
        #pragma unroll
        for (int nt = 0; nt < 4; nt++) {
            int col = wn + nt * 16 + lc;
            float bv_ = bias[n0 + col];
            #pragma unroll
            for (int mt = 0; mt < 4; mt++) {
                f16x4 v;
                #pragma unroll
                for (int r = 0; r < 4; r++) v[r] = (f16)(acc[mt][nt][r] + bv_);
                *(f16x4*)&lds.tr[col * 136 + wm + mt * 16 + quad * 4] = v;
            }
        }
        __syncthreads();
        const int bb = m0 >> 11;
        const int sbase = m0 & (S - 1);
        #pragma unroll
        for (int p = 0; p < 8; p++) {
            int chunk = tid + p * 256;          // 0..2047
            int col = chunk >> 4;               // 0..127
            int oct = chunk & 15;               // 8-m group
            f16x8 v = *(const f16x8*)&lds.tr[col * 136 + oct * 8];
            int gcol = n0 + col;
            int h = gcol >> 6, hd = gcol & 63;
            size_t idx = (((size_t)(bb * H + h) * HD) + hd) * S + sbase + oct * 8;
            *(f16x8*)(Vth + idx) = v;
        }
    }
}

// ---------------- output projection (MFMA) ----------------
__global__ __launch_bounds__(256) void out_mfma_k(
    const f16* __restrict__ oh, const f16* __restrict__ ol,
    const f16* __restrict__ wh,
    const float* __restrict__ bias, float* __restrict__ Y)
{
    __shared__ f16 Ah[128 * 32], Al[128 * 32], Bh[128 * 32];
    const int m0 = blockIdx.y * 128, n0 = blockIdx.x * 128;
    f32x4 acc[4][4];
    #pragma unroll
    for (int i = 0; i < 4; i++)
        #pragma unroll
        for (int j = 0; j < 4; j++) acc[i][j] = (f32x4){0.f, 0.f, 0.f, 0.f};

    gemm_core(oh, ol, wh, m0, n0, Ah, Al, Bh, acc);

    const int tid = threadIdx.x;
    const int w = tid >> 6, ln = tid & 63;
    const int wm = (w & 1) * 64, wn = (w >> 1) * 64;
    const int lc = ln & 15, quad = ln >> 4;

    #pragma unroll
    for (int nt = 0; nt < 4; nt++) {
        int col = n0 + wn + nt * 16 + lc;
        float bv_ = bias[col];
        #pragma unroll
        for (int mt = 0; mt < 4; mt++) {
            #pragma unroll
            for (int r = 0; r < 4; r++) {
                int m = m0 + wm + mt * 16 + quad * 4 + r;
                Y[(size_t)m * D + col] = acc[mt][nt][r] + bv_;
            }
        }
    }
}

// ---------------- MFMA block-diagonal flash attention (fp16 2-term) ----------------
__global__ __launch_bounds__(256) void attn3_k(
    const f16* __restrict__ Qh, const f16* __restrict__ Ql,
    const f16* __restrict__ Kh, const f16* __restrict__ Vth,
    const int* __restrict__ dstart, const int* __restrict__ dend,
    f16* __restrict__ Ohi, f16* __restrict__ Olo)
{
    const int qt = blockIdx.x, h = blockIdx.y, b = blockIdx.z;
    const int q0 = qt * TQ;
    const size_t bh  = ((size_t)b * H + h) * S;
    const size_t bhv = ((size_t)b * H + h) * HD;

    const int tid = threadIdx.x;
    const int w = tid >> 6, ln = tid & 63;
    const int lc = ln & 15, quad = ln >> 4;

    __shared__ f16 VtHs[64 * 64];        // [dim][key octet-swizzled]
    __shared__ float Ps[4][16 * 64];
    __shared__ int sb[TQ], se[TQ];

    if (tid < TQ) { sb[tid] = dstart[q0 + tid]; se[tid] = dend[q0 + tid]; }

    const size_t qrow = bh + q0 + w * 16 + lc;
    f16x8 qfh[2], qfl[2];
    #pragma unroll
    for (int ks = 0; ks < 2; ks++) {
        qfh[ks] = *(const f16x8*)(Qh + qrow * HD + ks * 32 + quad * 8);
        qfl[ks] = *(const f16x8*)(Ql + qrow * HD + ks * 32 + quad * 8);
    }
    __syncthreads();

    int row_st[4], row_en[4];
    #pragma unroll
    for (int r = 0; r < 4; r++) {
        row_st[r] = sb[w * 16 + quad * 4 + r];
        row_en[r] = se[w * 16 + quad * 4 + r];
    }
    const int kstart = sb[0] & ~63;
    const int kend   = se[TQ - 1];

    f32x4 o[4];
    #pragma unroll
    for (int nt = 0; nt < 4; nt++) o[nt] = (f32x4){0.f, 0.f, 0.f, 0.f};
    f32x4 m_i = (f32x4){NEGBIG, NEGBIG, NEGBIG, NEGBIG};
    f32x4 l_i = (f32x4){0.f, 0.f, 0.f, 0.f};

    for (int j0 = kstart; j0 < kend; j0 += 64) {
        __syncthreads();
        // stage V^T chunk (hi only)
        #pragma unroll
        for (int p = 0; p < 2; p++) {
            int idx = tid + p * 256;          // 0..511
            int dim = idx >> 3, g = idx & 7;
            int slot = g ^ (dim & 7);
            *(uint4*)&VtHs[dim * 64 + slot * 8] =
                *(const uint4*)(Vth + (bhv + dim) * S + j0 + g * 8);
        }

        f16x8 kfh[4][2];
        #pragma unroll
        for (int t = 0; t < 4; t++) {
            size_t krow = (bh + j0 + t * 16 + lc) * HD;
            #pragma unroll
            for (int ks = 0; ks < 2; ks++)
                kfh[t][ks] = *(const f16x8*)(Kh + krow + ks * 32 + quad * 8);
        }
        __syncthreads();

        // scores (Q pre-scaled): S[row=quad*4+r][key=t*16+lc]
        f32x4 sc[4];
        #pragma unroll
        for (int t = 0; t < 4; t++) {
            f32x4 a = (f32x4){0.f, 0.f, 0.f, 0.f};
            #pragma unroll
            for (int ks = 0; ks < 2; ks++) {
                a = __builtin_amdgcn_mfma_f32_16x16x32_f16(qfl[ks], kfh[t][ks], a, 0, 0, 0);
                a = __builtin_amdgcn_mfma_f32_16x16x32_f16(qfh[ks], kfh[t][ks], a, 0, 0, 0);
            }
            int key = j0 + t * 16 + lc;
            #pragma unroll
            for (int r = 0; r < 4; r++) {
                bool valid = (key >= row_st[r]) && (key < row_en[r]);
                sc[t][r] = valid ? a[r] : NEGBIG;
            }
        }

        // online softmax (16 rows at once)
        f32x4 mx = sc[0];
        #pragma unroll
        for (int t = 1; t < 4; t++)
            #pragma unroll
            for (int r = 0; r < 4; r++) mx[r] = fmaxf(mx[r], sc[t][r]);
        #pragma unroll
        for (int off = 1; off <= 8; off <<= 1)
            #pragma unroll
            for (int r = 0; r < 4; r++) mx[r] = fmaxf(mx[r], __shfl_xor(mx[r], off, 64));

        f32x4 m_new, alpha;
        #pragma unroll
        for (int r = 0; r < 4; r++) {
            m_new[r] = fmaxf(m_i[r], mx[r]);
            alpha[r] = __expf(m_i[r] - m_new[r]);
        }

        f32x4 psum = (f32x4){0.f, 0.f, 0.f, 0.f};
        f32x4 pv[4];
        #pragma unroll
        for (int t = 0; t < 4; t++) {
            #pragma unroll
            for (int r = 0; r < 4; r++) {
                float p = __expf(sc[t][r] - m_new[r]);
                p = (sc[t][r] < -5e29f) ? 0.f : p;
                pv[t][r] = p;
                psum[r] += p;
            }
        }
        #pragma unroll
        for (int off = 1; off <= 8; off <<= 1)
            #pragma unroll
            for (int r = 0; r < 4; r++) psum[r] += __shfl_xor(psum[r], off, 64);

        #pragma unroll
        for (int r = 0; r < 4; r++) {
            l_i[r] = l_i[r] * alpha[r] + psum[r];
            m_i[r] = m_new[r];
        }
        #pragma unroll
        for (int nt = 0; nt < 4; nt++)
            #pragma unroll
            for (int r = 0; r < 4; r++) o[nt][r] *= alpha[r];

        // P -> LDS (C-layout -> swizzled [q][key])
        #pragma unroll
        for (int t = 0; t < 4; t++) {
            int g = 2 * t + (lc >> 3);
            #pragma unroll
            for (int r = 0; r < 4; r++) {
                int q = quad * 4 + r;
                Ps[w][q * 64 + ((g ^ (q & 7)) * 8) + (lc & 7)] = pv[t][r];
            }
        }
        __syncthreads();

        // PV: O += (Ph + Pl) * Vh
        #pragma unroll
        for (int ks = 0; ks < 2; ks++) {
            int gp = ks * 4 + quad;
            const float* prow = &Ps[w][lc * 64 + ((gp ^ (lc & 7)) * 8)];
            f16x8 ph, pl;
            #pragma unroll
            for (int j = 0; j < 8; j++) {
                float f = prow[j];
                f16 hh = (f16)f;
                ph[j] = hh;
                pl[j] = (f16)(f - (float)hh);
            }
            #pragma unroll
            for (int nt = 0; nt < 4; nt++) {
                int dim = nt * 16 + lc;
                int slot = gp ^ (dim & 7);
                f16x8 vh = *(const f16x8*)&VtHs[dim * 64 + slot * 8];
                o[nt] = __builtin_amdgcn_mfma_f32_16x16x32_f16(pl, vh, o[nt], 0, 0, 0);
                o[nt] = __builtin_amdgcn_mfma_f32_16x16x32_f16(ph, vh, o[nt], 0, 0, 0);
            }
        }
    }

    // epilogue: O[(b*S+q)*D + h*64 + dim], hi/lo fp16 for out-proj
    f32x4 inv;
    #pragma unroll
    for (int r = 0; r < 4; r++) inv[r] = 1.f / l_i[r];
    #pragma unroll
    for (int nt = 0; nt < 4; nt++) {
        int dim = nt * 16 + lc;
        #pragma unroll
        for (int r = 0; r < 4; r++) {
            int q = q0 + w * 16 + quad * 4 + r;
            float val = o[nt][r] * inv[r];
            size_t idx = ((size_t)(b * S + q)) * D + h * 64 + dim;
            f16 hh = (f16)val;
            Ohi[idx] = hh;
            Olo[idx] = (f16)(val - (float)hh);
        }
    }
}

extern "C" void kernel_launch(void* const* d_in, const int* in_sizes, int n_in,
                              void* d_out, int out_size, void* d_ws, size_t ws_size,
                              hipStream_t stream) {
    const float* hs = (const float*)d_in[0];
    const float* wq = (const float*)d_in[1];
    const float* bq = (const float*)d_in[2];
    const float* wk = (const float*)d_in[3];
    const float* bk = (const float*)d_in[4];
    const float* wv = (const float*)d_in[5];
    const float* bv = (const float*)d_in[6];
    const float* wo = (const float*)d_in[7];
    const float* bo = (const float*)d_in[8];
    const int*  doc = (const int*)d_in[9];
    float* out = (float*)d_out;

    const size_t NE = (size_t)B * S * D;       // 4,194,304
    const size_t NW = (size_t)D * D;           // 1,048,576
    f16* xh  = (f16*)d_ws;  f16* xl = xh + NE;   // reused as Ohi/Olo after qkv
    f16* Qhb = xl + NE;     f16* Qlb = Qhb + NE;
    f16* Khb = Qlb + NE;    f16* Vth = Khb + NE;
    f16* wqh = Vth + NE;
    f16* wkh = wqh + NW;
    f16* wvh = wkh + NW;
    f16* woh = wvh + NW;
    int* dstart = (int*)(woh + NW);
    int* dend = dstart + S;

    docbounds_k<<<(S + 255) / 256, 256, 0, stream>>>(doc, dstart, dend);
    split2_k<<<(int)(NE / 8 / 256), 256, 0, stream>>>((const float4*)hs, (f16x8*)xh, (f16x8*)xl, (int)(NE / 8));
    conv_k<<<(int)(NW / 8 / 256), 256, 0, stream>>>((const float4*)wq, (f16x8*)wqh, (int)(NW / 8));
    conv_k<<<(int)(NW / 8 / 256), 256, 0, stream>>>((const float4*)wk, (f16x8*)wkh, (int)(NW / 8));
    conv_k<<<(int)(NW / 8 / 256), 256, 0, stream>>>((const float4*)wv, (f16x8*)wvh, (int)(NW / 8));
    conv_k<<<(int)(NW / 8 / 256), 256, 0, stream>>>((const float4*)wo, (f16x8*)woh, (int)(NW / 8));

    qkv_mfma_k<<<dim3(D / 128, (B * S) / 128, 3), 256, 0, stream>>>(
        xh, xl, wqh, wkh, wvh, bq, bk, bv, Qhb, Qlb, Khb, Vth);
    attn3_k<<<dim3(S / TQ, H, B), 256, 0, stream>>>(
        Qhb, Qlb, Khb, Vth, dstart, dend, xh, xl);
    out_mfma_k<<<dim3(D / 128, (B * S) / 128), 256, 0, stream>>>(xh, xl, woh, bo, out);
}